// Round 17
// baseline (360.467 us; speedup 1.0000x reference)
//
#include <hip/hip_runtime.h>
#include <hip/hip_bf16.h>

#define HH 128      // hidden dim
#define BUK_SH 9    // 512 nodes per bucket
#define BUK 512
#define CAP 8192    // edge capacity per bucket (mean 4096, sigma ~64)

typedef __attribute__((ext_vector_type(8))) short short8;   // bf16x8 MFMA frag (4 VGPR)
typedef __attribute__((ext_vector_type(4))) float floatx4;  // MFMA acc frag
typedef __attribute__((ext_vector_type(2))) float floatx2;

__device__ __forceinline__ ushort f2bf(float f) {
    uint u = __float_as_uint(f);
    uint r = (u + 0x7FFFu + ((u >> 16) & 1u)) >> 16;
    return (ushort)r;
}
__device__ __forceinline__ float bflo(uint p) { return __uint_as_float(p << 16); }
__device__ __forceinline__ float bfhi(uint p) { return __uint_as_float(p & 0xFFFF0000u); }
__device__ __forceinline__ uint packbf(float a, float b) {
    return (uint)f2bf(a) | ((uint)f2bf(b) << 16);
}
__device__ __forceinline__ float bf2f(ushort u) { return __uint_as_float((uint)u << 16); }
// fp8 e4m3 (OCP) HW converts, gfx950
__device__ __forceinline__ uchar f2fp8(float v) {
    return (uchar)(__builtin_amdgcn_cvt_pk_fp8_f32(v, v, 0, false) & 0xFF);
}
// frag-permuted column position: contiguous 32B(fp8)/64B(bf16) per (row, aq)
__device__ __forceinline__ int permc(int c) {
    return (((c & 31) >> 3) << 5) + ((c >> 5) << 3) + (c & 7);
}

// ---------------- CSR build, bucketed (write-amp-free) ----------------

__global__ __launch_bounds__(256) void bin_k(
    const int* __restrict__ src, const int* __restrict__ dst,
    int* __restrict__ gcur, uint* __restrict__ ebuf, int E) {
    __shared__ int hist[256];
    __shared__ int base[256];
    int tid = threadIdx.x;
    hist[tid] = 0;
    __syncthreads();
    int e0 = blockIdx.x * 2048;
    int d[8];
#pragma unroll
    for (int i = 0; i < 8; i++) {
        int e = e0 + i * 256 + tid;
        d[i] = (e < E) ? dst[e] : -1;
        if (d[i] >= 0) atomicAdd(&hist[d[i] >> BUK_SH], 1);
    }
    __syncthreads();
    if (hist[tid] > 0) base[tid] = atomicAdd(&gcur[tid], hist[tid]);
    hist[tid] = 0;
    __syncthreads();
#pragma unroll
    for (int i = 0; i < 8; i++) {
        if (d[i] >= 0) {
            int e = e0 + i * 256 + tid;
            int b = d[i] >> BUK_SH;
            int p = base[b] + atomicAdd(&hist[b], 1);
            if (p < CAP)
                ebuf[(size_t)b * CAP + p] = ((uint)(d[i] & (BUK - 1)) << 17) | (uint)src[e];
        }
    }
}

// Per-bucket CSR + degree counting-sort into global order[] (gather balance).
__global__ __launch_bounds__(256) void build_k(
    const uint* __restrict__ ebuf, const int* __restrict__ gcur,
    int* __restrict__ offs, float* __restrict__ invd,
    int* __restrict__ csr, int* __restrict__ order, int N, int nbuk) {
    __shared__ int ncnt[BUK];
    __shared__ int npre[BUK];
    __shared__ int ss[256];
    __shared__ int csrbuf[CAP];
    __shared__ int dbase[64];
    __shared__ int dcur[64];
    int b = blockIdx.x, tid = threadIdx.x;

    int bc = (tid < nbuk) ? gcur[tid] : 0;
    if (bc > CAP) bc = CAP;
    ss[tid] = bc;
    __syncthreads();
    for (int o = 1; o < 256; o <<= 1) {
        int tv = (tid >= o) ? ss[tid - o] : 0;
        __syncthreads();
        ss[tid] += tv;
        __syncthreads();
    }
    int cnt = gcur[b]; if (cnt > CAP) cnt = CAP;
    int base = ss[b] - cnt;
    __syncthreads();

    ncnt[tid] = 0; ncnt[tid + 256] = 0;
    if (tid < 64) { dbase[tid] = 0; dcur[tid] = 0; }
    __syncthreads();
    const uint* eb = ebuf + (size_t)b * CAP;
    for (int i = tid; i < cnt; i += 256) atomicAdd(&ncnt[eb[i] >> 17], 1);
    __syncthreads();
    int a0 = ncnt[2 * tid], a1 = ncnt[2 * tid + 1];
    int pair = a0 + a1;
    ss[tid] = pair;
    __syncthreads();
    for (int o = 1; o < 256; o <<= 1) {
        int tv = (tid >= o) ? ss[tid - o] : 0;
        __syncthreads();
        ss[tid] += tv;
        __syncthreads();
    }
    int ep = ss[tid] - pair;
    npre[2 * tid] = ep;
    npre[2 * tid + 1] = ep + a0;
    __syncthreads();
    // offs/invd + degree histogram (degrees still live in ncnt)
#pragma unroll
    for (int q = 0; q < 2; q++) {
        int ln = q * 256 + tid;
        int node = b * BUK + ln;
        if (node < N) {
            offs[node] = base + npre[ln];
            int dg = ncnt[ln];
            invd[node] = 1.0f / (float)(dg > 1 ? dg : 1);
            int bin = dg < 63 ? dg : 63;
            atomicAdd(&dbase[bin], 1);
        }
    }
    __syncthreads();
    // exclusive scan of 64 degree bins (in ss[0..63])
    if (tid < 64) ss[tid] = dbase[tid];
    __syncthreads();
    for (int o = 1; o < 64; o <<= 1) {
        int tv = (tid < 64 && tid >= o) ? ss[tid - o] : 0;
        __syncthreads();
        if (tid < 64) ss[tid] += tv;
        __syncthreads();
    }
    if (tid < 64) dbase[tid] = ss[tid] - dbase[tid];
    __syncthreads();
    // scatter node ids into degree-sorted order (bucket-local slots)
#pragma unroll
    for (int q = 0; q < 2; q++) {
        int ln = q * 256 + tid;
        int node = b * BUK + ln;
        if (node < N) {
            int dg = ncnt[ln];
            int bin = dg < 63 ? dg : 63;
            int pos = dbase[bin] + atomicAdd(&dcur[bin], 1);
            order[b * BUK + pos] = node;
        }
    }
    __syncthreads();
    ncnt[2 * tid] = npre[2 * tid];
    ncnt[2 * tid + 1] = npre[2 * tid + 1];
    __syncthreads();
    for (int i = tid; i < cnt; i += 256) {
        uint pk = eb[i];
        int p = atomicAdd(&ncnt[pk >> 17], 1);
        csrbuf[p] = (int)(pk & 0x1FFFFu);
    }
    __syncthreads();
    for (int i = tid; i < cnt; i += 256) csr[base + i] = csrbuf[i];
    if (b == nbuk - 1 && tid == 0) offs[N] = base + cnt;
}

// ---------------- weight packing: [Wl;Wr] -> bf16 MFMA B-frag layout ----------------

__global__ __launch_bounds__(256) void prep_w_k(
    const float* __restrict__ Wl, const float* __restrict__ Wr, ushort* __restrict__ Bp) {
    int gid = blockIdx.x * 256 + threadIdx.x;
    int layer = gid >> 15;
    int r = gid & 32767;
    int j = r & 7;
    int lane = (r >> 3) & 63;
    int ct = (r >> 9) & 7;
    int ks = r >> 12;
    int k = ks * 32 + (lane >> 4) * 8 + j;
    int n = ct * 16 + (lane & 15);
    float v = (k < HH) ? Wl[(size_t)layer * HH * HH + k * HH + n]
                       : Wr[(size_t)layer * HH * HH + (k - HH) * HH + n];
    Bp[gid] = f2bf(v);
}

// ---------------- node encoder: bf16 + frag-permuted fp8 mirrors ----------------

__global__ __launch_bounds__(256) void encoder_k(
    const float* __restrict__ x, const float* __restrict__ W,
    const float* __restrict__ b, uint* __restrict__ hb, uchar* __restrict__ hf8, int N) {
    int n = blockIdx.x * 4 + (threadIdx.x >> 6);
    int j = threadIdx.x & 63;
    if (n >= N) return;
    float4 xv = *(const float4*)(x + (size_t)n * 4);
    float v0 = b[2 * j], v1 = b[2 * j + 1];
    v0 = fmaf(xv.x, W[0 * HH + 2 * j], v0); v1 = fmaf(xv.x, W[0 * HH + 2 * j + 1], v1);
    v0 = fmaf(xv.y, W[1 * HH + 2 * j], v0); v1 = fmaf(xv.y, W[1 * HH + 2 * j + 1], v1);
    v0 = fmaf(xv.z, W[2 * HH + 2 * j], v0); v1 = fmaf(xv.z, W[2 * HH + 2 * j + 1], v1);
    v0 = fmaf(xv.w, W[3 * HH + 2 * j], v0); v1 = fmaf(xv.w, W[3 * HH + 2 * j + 1], v1);
    v0 = fmaxf(v0, 0.0f); v1 = fmaxf(v1, 0.0f);
    hb[(size_t)n * 64 + j] = packbf(v0, v1);
    uint p8 = __builtin_amdgcn_cvt_pk_fp8_f32(v0, v1, 0, false);
    int pos = permc(2 * j);                  // even -> pair stays contiguous
    ((ushort*)hf8)[(size_t)n * 64 + (pos >> 1)] = (ushort)(p8 & 0xFFFF);
}

// ---------------- standalone gather: fp8 permuted -> bf16 permuted agg ----------------
// 8 lanes per node, nodes visited in degree-sorted order (order[]): waves see
// ~equal-degree nodes -> max/mean ~1 (was ~1.6 for Poisson(8) max-of-8).
// 8 requests/edge = structural floor (128B row / 16B loads).

__device__ __forceinline__ void acc16(float* a, uint4 p) {
    floatx2 v;
    v = __builtin_amdgcn_cvt_pk_f32_fp8(p.x, false); a[0] += v.x;  a[1] += v.y;
    v = __builtin_amdgcn_cvt_pk_f32_fp8(p.x, true);  a[2] += v.x;  a[3] += v.y;
    v = __builtin_amdgcn_cvt_pk_f32_fp8(p.y, false); a[4] += v.x;  a[5] += v.y;
    v = __builtin_amdgcn_cvt_pk_f32_fp8(p.y, true);  a[6] += v.x;  a[7] += v.y;
    v = __builtin_amdgcn_cvt_pk_f32_fp8(p.z, false); a[8] += v.x;  a[9] += v.y;
    v = __builtin_amdgcn_cvt_pk_f32_fp8(p.z, true);  a[10] += v.x; a[11] += v.y;
    v = __builtin_amdgcn_cvt_pk_f32_fp8(p.w, false); a[12] += v.x; a[13] += v.y;
    v = __builtin_amdgcn_cvt_pk_f32_fp8(p.w, true);  a[14] += v.x; a[15] += v.y;
}

__global__ __launch_bounds__(256) void aggregate_k(
    const uchar* __restrict__ hf8, const int* __restrict__ offs,
    const int* __restrict__ csr, const float* __restrict__ invd,
    const int* __restrict__ order, uint* __restrict__ aggb, int N) {
    int slot = blockIdx.x * 32 + (threadIdx.x >> 3);
    int j = threadIdx.x & 7;
    if (slot >= N) return;
    int n = order[slot];
    const uint4* h8 = (const uint4*)hf8;     // row stride = 8 uint4
    int s = offs[n], e = offs[n + 1];
    float ac[16];
#pragma unroll
    for (int k = 0; k < 16; k++) ac[k] = 0.0f;
    int i = s;
    for (; i + 4 <= e; i += 4) {
        int u0 = csr[i], u1 = csr[i + 1], u2 = csr[i + 2], u3 = csr[i + 3];
        uint4 p0 = h8[(size_t)u0 * 8 + j];
        uint4 p1 = h8[(size_t)u1 * 8 + j];
        uint4 p2 = h8[(size_t)u2 * 8 + j];
        uint4 p3 = h8[(size_t)u3 * 8 + j];
        acc16(ac, p0); acc16(ac, p1); acc16(ac, p2); acc16(ac, p3);
    }
    for (; i < e; i++) {
        uint4 p = h8[(size_t)csr[i] * 8 + j];
        acc16(ac, p);
    }
    float iv = invd[n];
    uint o[8];
#pragma unroll
    for (int k = 0; k < 8; k++) o[k] = packbf(ac[2 * k] * iv, ac[2 * k + 1] * iv);
    uint4* outp = (uint4*)(aggb + (size_t)n * 64 + j * 8);
    outp[0] = make_uint4(o[0], o[1], o[2], o[3]);
    outp[1] = make_uint4(o[4], o[5], o[6], o[7]);
}

// ---------------- fused SAGE layer (layers 1-2): MFMA + LN + residual -----------------
// A-frags stream from permuted bf16 aggb (lane: 4 contiguous 16B loads) and
// row-major hbin. No random loads. Ping-pong bf16+fp8 residual streams.

__global__ __launch_bounds__(256) void sage_mfma_k(
    const ushort* __restrict__ hbin, const uint* __restrict__ aggb,
    ushort* __restrict__ hbout, uchar* __restrict__ hf8out,
    const ushort* __restrict__ Bp, const float* __restrict__ bl,
    const float* __restrict__ g, const float* __restrict__ bln, int N) {
    int wave = threadIdx.x >> 6;
    int lane = threadIdx.x & 63;
    int m0 = blockIdx.x * 128 + wave * 32;
    int am = lane & 15, aq = lane >> 4;

    floatx4 acc[2][8];
#pragma unroll
    for (int rt = 0; rt < 2; rt++)
#pragma unroll
        for (int ct = 0; ct < 8; ct++) acc[rt][ct] = (floatx4)0.0f;

#pragma unroll
    for (int ks = 0; ks < 8; ks++) {
        short8 a[2];
#pragma unroll
        for (int rt = 0; rt < 2; rt++) {
            int row = m0 + rt * 16 + am;
            row = row < N ? row : N - 1;
            if (ks < 4) {
                a[rt] = *(const short8*)(aggb + (size_t)row * 64 + aq * 16 + ks * 4);
            } else {
                a[rt] = *(const short8*)(hbin + (size_t)row * HH + (ks & 3) * 32 + aq * 8);
            }
        }
#pragma unroll
        for (int ct = 0; ct < 8; ct++) {
            short8 b = *(const short8*)(Bp + (((size_t)(ks * 8 + ct)) * 64 + lane) * 8);
            acc[0][ct] = __builtin_amdgcn_mfma_f32_16x16x32_bf16(a[0], b, acc[0][ct], 0, 0, 0);
            acc[1][ct] = __builtin_amdgcn_mfma_f32_16x16x32_bf16(a[1], b, acc[1][ct], 0, 0, 0);
        }
    }

    int g4 = lane >> 4, cl = lane & 15;
    float bias[8], gam[8], bet[8];
#pragma unroll
    for (int ct = 0; ct < 8; ct++) {
        bias[ct] = bl[ct * 16 + cl];
        gam[ct] = g[ct * 16 + cl];
        bet[ct] = bln[ct * 16 + cl];
    }
#pragma unroll
    for (int rt = 0; rt < 2; rt++) {
        float sr[4], qr[4];
#pragma unroll
        for (int reg = 0; reg < 4; reg++) {
            float s = 0.0f, q = 0.0f;
#pragma unroll
            for (int ct = 0; ct < 8; ct++) {
                float v = acc[rt][ct][reg] + bias[ct];
                s += v;
                q += v * v;
            }
#pragma unroll
            for (int m = 1; m < 16; m <<= 1) {
                s += __shfl_xor(s, m);
                q += __shfl_xor(q, m);
            }
            sr[reg] = s;
            qr[reg] = q;
        }
#pragma unroll
        for (int reg = 0; reg < 4; reg++) {
            int row = m0 + rt * 16 + g4 * 4 + reg;
            if (row < N) {
                float mean = sr[reg] * (1.0f / 128.0f);
                float var = qr[reg] * (1.0f / 128.0f) - mean * mean;
                float rstd = rsqrtf(fmaxf(var, 0.0f) + 1e-5f);
#pragma unroll
                for (int ct = 0; ct < 8; ct++) {
                    float v = acc[rt][ct][reg] + bias[ct];
                    float r = fmaxf((v - mean) * rstd * gam[ct] + bet[ct], 0.0f);
                    int c = ct * 16 + cl;
                    size_t idx = (size_t)row * HH + c;
                    float nv = bf2f(hbin[idx]) + r;
                    hbout[idx] = f2bf(nv);
                    hf8out[(size_t)row * HH + permc(c)] = f2fp8(nv);
                }
            }
        }
    }
}

// ---------------- layer 3: SAGE + fused pooling (no residual writes) ----------------
// NOTE: shfl_xor(16|32) folds the 4 g4 quad-groups (8 DISTINCT rows each) ->
// result is already the wave count / column sum. No /16.

__global__ __launch_bounds__(256) void sage_pool_k(
    const ushort* __restrict__ hbin, const uint* __restrict__ aggb,
    const ushort* __restrict__ Bp, const float* __restrict__ bl,
    const float* __restrict__ g, const float* __restrict__ bln,
    const int* __restrict__ batch,
    float* __restrict__ psum, int* __restrict__ pmax, int* __restrict__ pcnt, int N) {
    __shared__ float wsum[4][128];
    __shared__ float wmax[4][128];
    __shared__ int wcnt[4];
    int tid = threadIdx.x;
    int wave = tid >> 6;
    int lane = tid & 63;
    int blk0 = blockIdx.x * 128;
    int m0 = blk0 + wave * 32;
    int am = lane & 15, aq = lane >> 4;

    floatx4 acc[2][8];
#pragma unroll
    for (int rt = 0; rt < 2; rt++)
#pragma unroll
        for (int ct = 0; ct < 8; ct++) acc[rt][ct] = (floatx4)0.0f;

#pragma unroll
    for (int ks = 0; ks < 8; ks++) {
        short8 a[2];
#pragma unroll
        for (int rt = 0; rt < 2; rt++) {
            int row = m0 + rt * 16 + am;
            row = row < N ? row : N - 1;
            if (ks < 4) {
                a[rt] = *(const short8*)(aggb + (size_t)row * 64 + aq * 16 + ks * 4);
            } else {
                a[rt] = *(const short8*)(hbin + (size_t)row * HH + (ks & 3) * 32 + aq * 8);
            }
        }
#pragma unroll
        for (int ct = 0; ct < 8; ct++) {
            short8 b = *(const short8*)(Bp + (((size_t)(ks * 8 + ct)) * 64 + lane) * 8);
            acc[0][ct] = __builtin_amdgcn_mfma_f32_16x16x32_bf16(a[0], b, acc[0][ct], 0, 0, 0);
            acc[1][ct] = __builtin_amdgcn_mfma_f32_16x16x32_bf16(a[1], b, acc[1][ct], 0, 0, 0);
        }
    }

    int g4 = lane >> 4, cl = lane & 15;
    float bias[8], gam[8], bet[8];
#pragma unroll
    for (int ct = 0; ct < 8; ct++) {
        bias[ct] = bl[ct * 16 + cl];
        gam[ct] = g[ct * 16 + cl];
        bet[ct] = bln[ct * 16 + cl];
    }
    // epilogue: nv = hbin + relu(LN(gemm+bias)), overwrite acc; rows >= N get 0
#pragma unroll
    for (int rt = 0; rt < 2; rt++) {
        float sr[4], qr[4];
#pragma unroll
        for (int reg = 0; reg < 4; reg++) {
            float s = 0.0f, q = 0.0f;
#pragma unroll
            for (int ct = 0; ct < 8; ct++) {
                float v = acc[rt][ct][reg] + bias[ct];
                s += v;
                q += v * v;
            }
#pragma unroll
            for (int m = 1; m < 16; m <<= 1) {
                s += __shfl_xor(s, m);
                q += __shfl_xor(q, m);
            }
            sr[reg] = s;
            qr[reg] = q;
        }
#pragma unroll
        for (int reg = 0; reg < 4; reg++) {
            int row = m0 + rt * 16 + g4 * 4 + reg;
            float mean = sr[reg] * (1.0f / 128.0f);
            float var = qr[reg] * (1.0f / 128.0f) - mean * mean;
            float rstd = rsqrtf(fmaxf(var, 0.0f) + 1e-5f);
            if (row < N) {
#pragma unroll
                for (int ct = 0; ct < 8; ct++) {
                    float v = acc[rt][ct][reg] + bias[ct];
                    float r = fmaxf((v - mean) * rstd * gam[ct] + bet[ct], 0.0f);
                    acc[rt][ct][reg] = bf2f(hbin[(size_t)row * HH + ct * 16 + cl]) + r;
                }
            } else {
#pragma unroll
                for (int ct = 0; ct < 8; ct++) acc[rt][ct][reg] = 0.0f;
            }
        }
    }

    bool fast = (blk0 + 127 < N) && (batch[blk0] == batch[blk0 + 127]);
    if (fast) {
        int b0 = batch[blk0];
#pragma unroll
        for (int ct = 0; ct < 8; ct++) {
            float s = 0.0f, m = 0.0f;
#pragma unroll
            for (int rt = 0; rt < 2; rt++)
#pragma unroll
                for (int reg = 0; reg < 4; reg++) {
                    float v = acc[rt][ct][reg];
                    s += v;
                    m = fmaxf(m, v);
                }
            s += __shfl_xor(s, 16); m = fmaxf(m, __shfl_xor(m, 16));
            s += __shfl_xor(s, 32); m = fmaxf(m, __shfl_xor(m, 32));
            if (g4 == 0) {
                wsum[wave][ct * 16 + cl] = s;
                wmax[wave][ct * 16 + cl] = m;
            }
        }
        __syncthreads();
        if (tid < 128) {
            float s = (wsum[0][tid] + wsum[1][tid]) + (wsum[2][tid] + wsum[3][tid]);
            float m = fmaxf(fmaxf(wmax[0][tid], wmax[1][tid]),
                            fmaxf(wmax[2][tid], wmax[3][tid]));
            atomicAdd(&psum[b0 * HH + tid], s);
            atomicMax(&pmax[b0 * HH + tid], __float_as_int(m));
        }
        if (tid == 0) atomicAdd(&pcnt[b0], 128);
    } else {
        int nlast = (blk0 + 127 < N - 1) ? blk0 + 127 : N - 1;
        int bfirst = batch[blk0];
        int blast = batch[nlast];
        int brow[2][4];
#pragma unroll
        for (int rt = 0; rt < 2; rt++)
#pragma unroll
            for (int reg = 0; reg < 4; reg++) {
                int row = m0 + rt * 16 + g4 * 4 + reg;
                brow[rt][reg] = (row < N) ? batch[row] : -1;
            }
        for (int b = bfirst; b <= blast; b++) {
            int c = 0;
#pragma unroll
            for (int rt = 0; rt < 2; rt++)
#pragma unroll
                for (int reg = 0; reg < 4; reg++) c += (brow[rt][reg] == b) ? 1 : 0;
            c += __shfl_xor(c, 16);
            c += __shfl_xor(c, 32);   // 4 g4 groups x 8 distinct rows = wave count
#pragma unroll
            for (int ct = 0; ct < 8; ct++) {
                float s = 0.0f, m = 0.0f;
#pragma unroll
                for (int rt = 0; rt < 2; rt++)
#pragma unroll
                    for (int reg = 0; reg < 4; reg++) {
                        if (brow[rt][reg] == b) {
                            float v = acc[rt][ct][reg];
                            s += v;
                            m = fmaxf(m, v);
                        }
                    }
                s += __shfl_xor(s, 16); m = fmaxf(m, __shfl_xor(m, 16));
                s += __shfl_xor(s, 32); m = fmaxf(m, __shfl_xor(m, 32));
                if (g4 == 0) {
                    wsum[wave][ct * 16 + cl] = s;
                    wmax[wave][ct * 16 + cl] = m;
                }
            }
            if (lane == 0) wcnt[wave] = c;
            __syncthreads();
            if (tid < 128) {
                float s = (wsum[0][tid] + wsum[1][tid]) + (wsum[2][tid] + wsum[3][tid]);
                float m = fmaxf(fmaxf(wmax[0][tid], wmax[1][tid]),
                                fmaxf(wmax[2][tid], wmax[3][tid]));
                atomicAdd(&psum[b * HH + tid], s);
                atomicMax(&pmax[b * HH + tid], __float_as_int(m));
            }
            if (tid == 0)
                atomicAdd(&pcnt[b], wcnt[0] + wcnt[1] + wcnt[2] + wcnt[3]);
            __syncthreads();
        }
    }
}

// ---------------- head: trackster MLP + concat + LN + classifier ----------------

__global__ __launch_bounds__(128) void head_k(
    const float* __restrict__ psum, const float* __restrict__ pmax,
    const int* __restrict__ pcnt, const float* __restrict__ ts,
    const float* __restrict__ tsW1, const float* __restrict__ tsb1,
    const float* __restrict__ tslng, const float* __restrict__ tslnb,
    const float* __restrict__ tsW2, const float* __restrict__ tsb2,
    const float* __restrict__ clng, const float* __restrict__ clnb,
    const float* __restrict__ cW1, const float* __restrict__ cb1,
    const float* __restrict__ cW2, const float* __restrict__ cb2,
    float* __restrict__ out) {
    int b = blockIdx.x;
    int t = threadIdx.x;
    __shared__ float feat[320];
    __shared__ float tn[64];
    __shared__ float zz[128];
    __shared__ float ps[2], pq[2];

    if (t < 64) {
        float v = tsb1[t];
#pragma unroll
        for (int k = 0; k < 3; k++) v = fmaf(ts[b * 3 + k], tsW1[k * 64 + t], v);
        float s = v, q = v * v;
#pragma unroll
        for (int m = 1; m < 64; m <<= 1) {
            s += __shfl_xor(s, m);
            q += __shfl_xor(q, m);
        }
        float mean = s * (1.0f / 64.0f);
        float var = q * (1.0f / 64.0f) - mean * mean;
        float rstd = rsqrtf(fmaxf(var, 0.0f) + 1e-5f);
        tn[t] = fmaxf((v - mean) * rstd * tslng[t] + tslnb[t], 0.0f);
    }
    __syncthreads();
    if (t < 64) {
        float v = tsb2[t];
        for (int k = 0; k < 64; k++) v = fmaf(tn[k], tsW2[k * 64 + t], v);
        feat[256 + t] = v;
    }
    float cntf = (float)(pcnt[b] > 1 ? pcnt[b] : 1);
    feat[t] = psum[b * HH + t] / cntf;
    feat[128 + t] = pmax[b * HH + t];
    __syncthreads();

    float s = 0.0f, q = 0.0f;
    for (int i = t; i < 320; i += 128) {
        float v = feat[i];
        s += v;
        q += v * v;
    }
#pragma unroll
    for (int m = 1; m < 64; m <<= 1) {
        s += __shfl_xor(s, m);
        q += __shfl_xor(q, m);
    }
    if ((t & 63) == 0) { ps[t >> 6] = s; pq[t >> 6] = q; }
    __syncthreads();
    float S = ps[0] + ps[1], Q = pq[0] + pq[1];
    float mean = S * (1.0f / 320.0f);
    float var = Q * (1.0f / 320.0f) - mean * mean;
    float rstd = rsqrtf(fmaxf(var, 0.0f) + 1e-5f);
    for (int i = t; i < 320; i += 128)
        feat[i] = (feat[i] - mean) * rstd * clng[i] + clnb[i];
    __syncthreads();

    {
        float v = cb1[t];
        for (int k = 0; k < 320; k++) v = fmaf(feat[k], cW1[k * HH + t], v);
        zz[t] = fmaxf(v, 0.0f);
    }
    __syncthreads();
    if (t < 8) {
        float v = cb2[t];
        for (int k = 0; k < 128; k++) v = fmaf(zz[k], cW2[k * 8 + t], v);
        out[b * 8 + t] = v;
    }
}

// ---------------- launcher ----------------

extern "C" void kernel_launch(void* const* d_in, const int* in_sizes, int n_in,
                              void* d_out, int out_size, void* d_ws, size_t ws_size,
                              hipStream_t stream) {
    const int N = in_sizes[0] / 4;
    const int E = in_sizes[1] / 2;
    const int B = in_sizes[3] / 3;
    const int nbuk = (N + BUK - 1) >> BUK_SH;   // <= 256 for N <= 131072

    const float* x    = (const float*)d_in[0];
    const int*   ei   = (const int*)d_in[1];
    const int*   srcv = ei;
    const int*   dstv = ei + E;
    const int*   batch = (const int*)d_in[2];
    const float* ts   = (const float*)d_in[3];
    const float* encW = (const float*)d_in[4];
    const float* encb = (const float*)d_in[5];
    const float* sageWl = (const float*)d_in[6];
    const float* sagebl = (const float*)d_in[7];
    const float* sageWr = (const float*)d_in[8];
    const float* lng  = (const float*)d_in[9];
    const float* lnb  = (const float*)d_in[10];
    const float* tsW1 = (const float*)d_in[11];
    const float* tsb1 = (const float*)d_in[12];
    const float* tslng = (const float*)d_in[13];
    const float* tslnb = (const float*)d_in[14];
    const float* tsW2 = (const float*)d_in[15];
    const float* tsb2 = (const float*)d_in[16];
    const float* clng = (const float*)d_in[17];
    const float* clnb = (const float*)d_in[18];
    const float* cW1  = (const float*)d_in[19];
    const float* cb1  = (const float*)d_in[20];
    const float* cW2  = (const float*)d_in[21];
    const float* cb2  = (const float*)d_in[22];
    float* out = (float*)d_out;

    char* w = (char*)d_ws;
    size_t off = 0;
    auto take = [&](size_t bytes) -> void* {
        void* p = w + off;
        off = (off + bytes + 255) & ~(size_t)255;
        return p;
    };
    uint*  hb0  = (uint*)take((size_t)N * HH * 2);    // bf16 residual (ping)
    uint*  hb1  = (uint*)take((size_t)N * HH * 2);    // bf16 residual (pong)
    uchar* hf80 = (uchar*)take((size_t)N * HH);       // fp8 frag-permuted mirror (ping)
    uchar* hf81 = (uchar*)take((size_t)N * HH);       // fp8 frag-permuted mirror (pong)
    uint*  aggb = (uint*)take((size_t)N * HH * 2);    // bf16 frag-permuted aggregate
    ushort* Bp  = (ushort*)take((size_t)3 * HH * 2 * HH * 2); // packed weights
    int*   csr  = (int*)take((size_t)E * 4);
    int*   offs = (int*)take((size_t)(N + 1) * 4);
    float* invd = (float*)take((size_t)N * 4);
    int*   order = (int*)take((size_t)N * 4);         // degree-sorted node order
    uint*  ebuf = (uint*)take((size_t)nbuk * CAP * 4);
    // zero-initialized block (contiguous -> one memset)
    size_t z0 = off;
    int*   gcur = (int*)take(256 * 4);
    float* psum = (float*)take((size_t)B * HH * 4);
    int*   pmax = (int*)take((size_t)B * HH * 4);
    int*   pcnt = (int*)take((size_t)B * 4);
    size_t z1 = off;

    hipMemsetAsync(w + z0, 0, z1 - z0, stream);

    bin_k<<<(E + 2047) / 2048, 256, 0, stream>>>(srcv, dstv, gcur, ebuf, E);
    build_k<<<nbuk, 256, 0, stream>>>(ebuf, gcur, offs, invd, csr, order, N, nbuk);

    prep_w_k<<<384, 256, 0, stream>>>(sageWl, sageWr, Bp);
    encoder_k<<<(N + 3) / 4, 256, 0, stream>>>(x, encW, encb, hb0, hf80, N);

    int nblk = (N + 127) / 128;
    int ablk = (N + 31) / 32;
    // layer 0: (hb0,hf80) -> (hb1,hf81)
    aggregate_k<<<ablk, 256, 0, stream>>>(hf80, offs, csr, invd, order, aggb, N);
    sage_mfma_k<<<nblk, 256, 0, stream>>>(
        (const ushort*)hb0, aggb, (ushort*)hb1, hf81, Bp,
        sagebl, lng, lnb, N);
    // layer 1: (hb1,hf81) -> (hb0,hf80)
    aggregate_k<<<ablk, 256, 0, stream>>>(hf81, offs, csr, invd, order, aggb, N);
    sage_mfma_k<<<nblk, 256, 0, stream>>>(
        (const ushort*)hb1, aggb, (ushort*)hb0, hf80, Bp + (size_t)32768,
        sagebl + (size_t)HH, lng + (size_t)HH, lnb + (size_t)HH, N);
    // layer 2 fused with pooling: reads (hb0, aggb)
    aggregate_k<<<ablk, 256, 0, stream>>>(hf80, offs, csr, invd, order, aggb, N);
    sage_pool_k<<<nblk, 256, 0, stream>>>(
        (const ushort*)hb0, aggb, Bp + (size_t)2 * 32768,
        sagebl + (size_t)2 * HH, lng + (size_t)2 * HH, lnb + (size_t)2 * HH,
        batch, psum, pmax, pcnt, N);

    head_k<<<B, 128, 0, stream>>>(psum, (const float*)pmax, pcnt, ts,
                                  tsW1, tsb1, tslng, tslnb, tsW2, tsb2,
                                  clng, clnb, cW1, cb1, cW2, cb2, out);
}

// Round 18
// 343.577 us; speedup vs baseline: 1.0492x; 1.0492x over previous
//
#include <hip/hip_runtime.h>
#include <hip/hip_bf16.h>

#define HH 128      // hidden dim
#define BUK_SH 9    // 512 nodes per bucket
#define BUK 512
#define CAP 8192    // edge capacity per bucket (mean 4096, sigma ~64)

typedef __attribute__((ext_vector_type(8))) short short8;   // bf16x8 MFMA frag (4 VGPR)
typedef __attribute__((ext_vector_type(4))) float floatx4;  // MFMA acc frag
typedef __attribute__((ext_vector_type(2))) float floatx2;

__device__ __forceinline__ ushort f2bf(float f) {
    uint u = __float_as_uint(f);
    uint r = (u + 0x7FFFu + ((u >> 16) & 1u)) >> 16;
    return (ushort)r;
}
__device__ __forceinline__ float bflo(uint p) { return __uint_as_float(p << 16); }
__device__ __forceinline__ float bfhi(uint p) { return __uint_as_float(p & 0xFFFF0000u); }
__device__ __forceinline__ uint packbf(float a, float b) {
    return (uint)f2bf(a) | ((uint)f2bf(b) << 16);
}
__device__ __forceinline__ float bf2f(ushort u) { return __uint_as_float((uint)u << 16); }
// fp8 e4m3 (OCP) HW converts, gfx950
__device__ __forceinline__ uchar f2fp8(float v) {
    return (uchar)(__builtin_amdgcn_cvt_pk_fp8_f32(v, v, 0, false) & 0xFF);
}
// frag-permuted fp8 column position: contiguous 32B per (row, aq-quad)
__device__ __forceinline__ int permc(int c) {
    return (((c & 31) >> 3) << 5) + ((c >> 5) << 3) + (c & 7);
}

// ---------------- CSR build, bucketed (write-amp-free) ----------------

__global__ __launch_bounds__(256) void bin_k(
    const int* __restrict__ src, const int* __restrict__ dst,
    int* __restrict__ gcur, uint* __restrict__ ebuf, int E) {
    __shared__ int hist[256];
    __shared__ int base[256];
    int tid = threadIdx.x;
    hist[tid] = 0;
    __syncthreads();
    int e0 = blockIdx.x * 2048;
    int d[8];
#pragma unroll
    for (int i = 0; i < 8; i++) {
        int e = e0 + i * 256 + tid;
        d[i] = (e < E) ? dst[e] : -1;
        if (d[i] >= 0) atomicAdd(&hist[d[i] >> BUK_SH], 1);
    }
    __syncthreads();
    if (hist[tid] > 0) base[tid] = atomicAdd(&gcur[tid], hist[tid]);
    hist[tid] = 0;
    __syncthreads();
#pragma unroll
    for (int i = 0; i < 8; i++) {
        if (d[i] >= 0) {
            int e = e0 + i * 256 + tid;
            int b = d[i] >> BUK_SH;
            int p = base[b] + atomicAdd(&hist[b], 1);
            if (p < CAP)
                ebuf[(size_t)b * CAP + p] = ((uint)(d[i] & (BUK - 1)) << 17) | (uint)src[e];
        }
    }
}

__global__ __launch_bounds__(256) void build_k(
    const uint* __restrict__ ebuf, const int* __restrict__ gcur,
    int* __restrict__ offs, float* __restrict__ invd,
    int* __restrict__ csr, int N, int nbuk) {
    __shared__ int ncnt[BUK];
    __shared__ int npre[BUK];
    __shared__ int ss[256];
    __shared__ int csrbuf[CAP];
    int b = blockIdx.x, tid = threadIdx.x;

    int bc = (tid < nbuk) ? gcur[tid] : 0;
    if (bc > CAP) bc = CAP;
    ss[tid] = bc;
    __syncthreads();
    for (int o = 1; o < 256; o <<= 1) {
        int tv = (tid >= o) ? ss[tid - o] : 0;
        __syncthreads();
        ss[tid] += tv;
        __syncthreads();
    }
    int cnt = gcur[b]; if (cnt > CAP) cnt = CAP;
    int base = ss[b] - cnt;
    __syncthreads();

    ncnt[tid] = 0; ncnt[tid + 256] = 0;
    __syncthreads();
    const uint* eb = ebuf + (size_t)b * CAP;
    for (int i = tid; i < cnt; i += 256) atomicAdd(&ncnt[eb[i] >> 17], 1);
    __syncthreads();
    int a0 = ncnt[2 * tid], a1 = ncnt[2 * tid + 1];
    int pair = a0 + a1;
    ss[tid] = pair;
    __syncthreads();
    for (int o = 1; o < 256; o <<= 1) {
        int tv = (tid >= o) ? ss[tid - o] : 0;
        __syncthreads();
        ss[tid] += tv;
        __syncthreads();
    }
    int ep = ss[tid] - pair;
    npre[2 * tid] = ep;
    npre[2 * tid + 1] = ep + a0;
    __syncthreads();
#pragma unroll
    for (int q = 0; q < 2; q++) {
        int ln = q * 256 + tid;
        int node = b * BUK + ln;
        if (node < N) {
            offs[node] = base + npre[ln];
            int dg = ncnt[ln];
            invd[node] = 1.0f / (float)(dg > 1 ? dg : 1);
        }
    }
    __syncthreads();
    ncnt[2 * tid] = npre[2 * tid];
    ncnt[2 * tid + 1] = npre[2 * tid + 1];
    __syncthreads();
    for (int i = tid; i < cnt; i += 256) {
        uint pk = eb[i];
        int p = atomicAdd(&ncnt[pk >> 17], 1);
        csrbuf[p] = (int)(pk & 0x1FFFFu);
    }
    __syncthreads();
    for (int i = tid; i < cnt; i += 256) csr[base + i] = csrbuf[i];
    if (b == nbuk - 1 && tid == 0) offs[N] = base + cnt;
}

// ---------------- weight packing: [Wl;Wr] -> bf16 MFMA B-frag layout ----------------

__global__ __launch_bounds__(256) void prep_w_k(
    const float* __restrict__ Wl, const float* __restrict__ Wr, ushort* __restrict__ Bp) {
    int gid = blockIdx.x * 256 + threadIdx.x;
    int layer = gid >> 15;
    int r = gid & 32767;
    int j = r & 7;
    int lane = (r >> 3) & 63;
    int ct = (r >> 9) & 7;
    int ks = r >> 12;
    int k = ks * 32 + (lane >> 4) * 8 + j;
    int n = ct * 16 + (lane & 15);
    float v = (k < HH) ? Wl[(size_t)layer * HH * HH + k * HH + n]
                       : Wr[(size_t)layer * HH * HH + (k - HH) * HH + n];
    Bp[gid] = f2bf(v);
}

// ---------------- node encoder: bf16 + frag-permuted fp8 mirrors ----------------

__global__ __launch_bounds__(256) void encoder_k(
    const float* __restrict__ x, const float* __restrict__ W,
    const float* __restrict__ b, uint* __restrict__ hb, uchar* __restrict__ hf8, int N) {
    int n = blockIdx.x * 4 + (threadIdx.x >> 6);
    int j = threadIdx.x & 63;
    if (n >= N) return;
    float4 xv = *(const float4*)(x + (size_t)n * 4);
    float v0 = b[2 * j], v1 = b[2 * j + 1];
    v0 = fmaf(xv.x, W[0 * HH + 2 * j], v0); v1 = fmaf(xv.x, W[0 * HH + 2 * j + 1], v1);
    v0 = fmaf(xv.y, W[1 * HH + 2 * j], v0); v1 = fmaf(xv.y, W[1 * HH + 2 * j + 1], v1);
    v0 = fmaf(xv.z, W[2 * HH + 2 * j], v0); v1 = fmaf(xv.z, W[2 * HH + 2 * j + 1], v1);
    v0 = fmaf(xv.w, W[3 * HH + 2 * j], v0); v1 = fmaf(xv.w, W[3 * HH + 2 * j + 1], v1);
    v0 = fmaxf(v0, 0.0f); v1 = fmaxf(v1, 0.0f);
    hb[(size_t)n * 64 + j] = packbf(v0, v1);
    uint p8 = __builtin_amdgcn_cvt_pk_fp8_f32(v0, v1, 0, false);
    int pos = permc(2 * j);                  // even -> pair stays contiguous
    ((ushort*)hf8)[(size_t)n * 64 + (pos >> 1)] = (ushort)(p8 & 0xFFFF);
}

// ---------------- fused gather: frag-permuted fp8 neighbor-mean ----------------
// Lane (am=row, aq): its 32 needed cols are contiguous 32B at offset aq*32 in
// the permuted fp8 row -> 2 uint4 loads per neighbor. 2-neighbor unroll
// (R12: 4-unroll -> VGPR cliff). This is the best-measured gather form (R15).

__device__ __forceinline__ void acc_u32(float* a, uint u) {
    floatx2 lo = __builtin_amdgcn_cvt_pk_f32_fp8(u, false);
    floatx2 hi = __builtin_amdgcn_cvt_pk_f32_fp8(u, true);
    a[0] += lo.x; a[1] += lo.y; a[2] += hi.x; a[3] += hi.y;
}

__device__ __forceinline__ void gather_agg(
    const uchar* __restrict__ hf8, const int* __restrict__ offs,
    const int* __restrict__ csr, const float* __restrict__ invd,
    int row, int aq, short8* out) {
    const uint4* h8 = (const uint4*)hf8;   // row stride = 8 uint4
    int s = offs[row], e = offs[row + 1];
    float iv = invd[row];
    float ac[4][8];
#pragma unroll
    for (int q = 0; q < 4; q++)
#pragma unroll
        for (int c = 0; c < 8; c++) ac[q][c] = 0.0f;
    int i = s;
    for (; i + 2 <= e; i += 2) {
        int u0 = csr[i], u1 = csr[i + 1];
        uint4 pa0 = h8[(size_t)u0 * 8 + aq * 2];
        uint4 pb0 = h8[(size_t)u0 * 8 + aq * 2 + 1];
        uint4 pa1 = h8[(size_t)u1 * 8 + aq * 2];
        uint4 pb1 = h8[(size_t)u1 * 8 + aq * 2 + 1];
        acc_u32(&ac[0][0], pa0.x); acc_u32(&ac[0][4], pa0.y);
        acc_u32(&ac[1][0], pa0.z); acc_u32(&ac[1][4], pa0.w);
        acc_u32(&ac[2][0], pb0.x); acc_u32(&ac[2][4], pb0.y);
        acc_u32(&ac[3][0], pb0.z); acc_u32(&ac[3][4], pb0.w);
        acc_u32(&ac[0][0], pa1.x); acc_u32(&ac[0][4], pa1.y);
        acc_u32(&ac[1][0], pa1.z); acc_u32(&ac[1][4], pa1.w);
        acc_u32(&ac[2][0], pb1.x); acc_u32(&ac[2][4], pb1.y);
        acc_u32(&ac[3][0], pb1.z); acc_u32(&ac[3][4], pb1.w);
    }
    for (; i < e; i++) {
        int u = csr[i];
        uint4 pa = h8[(size_t)u * 8 + aq * 2];
        uint4 pb = h8[(size_t)u * 8 + aq * 2 + 1];
        acc_u32(&ac[0][0], pa.x); acc_u32(&ac[0][4], pa.y);
        acc_u32(&ac[1][0], pa.z); acc_u32(&ac[1][4], pa.w);
        acc_u32(&ac[2][0], pb.x); acc_u32(&ac[2][4], pb.y);
        acc_u32(&ac[3][0], pb.z); acc_u32(&ac[3][4], pb.w);
    }
#pragma unroll
    for (int q = 0; q < 4; q++) {
        short8 o;
#pragma unroll
        for (int c = 0; c < 8; c++) o[c] = (short)f2bf(ac[q][c] * iv);
        out[q] = o;
    }
}

// ---------------- fused SAGE layer (layers 1-2): gather + MFMA + LN + residual ----------
// 32 rows/wave, 128 rows/block. Ping-pong bf16+fp8 residual streams.

__global__ __launch_bounds__(256) void sage_mfma_k(
    const ushort* __restrict__ hbin, const uchar* __restrict__ hf8in,
    ushort* __restrict__ hbout, uchar* __restrict__ hf8out,
    const int* __restrict__ offs, const int* __restrict__ csr,
    const float* __restrict__ invd, const ushort* __restrict__ Bp,
    const float* __restrict__ bl, const float* __restrict__ g,
    const float* __restrict__ bln, int N) {
    int wave = threadIdx.x >> 6;
    int lane = threadIdx.x & 63;
    int m0 = blockIdx.x * 128 + wave * 32;
    int am = lane & 15, aq = lane >> 4;

    short8 a_agg[2][4];
#pragma unroll
    for (int rt = 0; rt < 2; rt++) {
        int row = m0 + rt * 16 + am;
        row = row < N ? row : N - 1;
        gather_agg(hf8in, offs, csr, invd, row, aq, a_agg[rt]);
    }

    floatx4 acc[2][8];
#pragma unroll
    for (int rt = 0; rt < 2; rt++)
#pragma unroll
        for (int ct = 0; ct < 8; ct++) acc[rt][ct] = (floatx4)0.0f;

#pragma unroll
    for (int ks = 0; ks < 8; ks++) {
        short8 a[2];
        if (ks < 4) {
            a[0] = a_agg[0][ks];
            a[1] = a_agg[1][ks];
        } else {
            int kc = (ks & 3) * 32 + aq * 8;
#pragma unroll
            for (int rt = 0; rt < 2; rt++) {
                int row = m0 + rt * 16 + am;
                row = row < N ? row : N - 1;
                a[rt] = *(const short8*)(hbin + (size_t)row * HH + kc);
            }
        }
#pragma unroll
        for (int ct = 0; ct < 8; ct++) {
            short8 b = *(const short8*)(Bp + (((size_t)(ks * 8 + ct)) * 64 + lane) * 8);
            acc[0][ct] = __builtin_amdgcn_mfma_f32_16x16x32_bf16(a[0], b, acc[0][ct], 0, 0, 0);
            acc[1][ct] = __builtin_amdgcn_mfma_f32_16x16x32_bf16(a[1], b, acc[1][ct], 0, 0, 0);
        }
    }

    int g4 = lane >> 4, cl = lane & 15;
    float bias[8], gam[8], bet[8];
#pragma unroll
    for (int ct = 0; ct < 8; ct++) {
        bias[ct] = bl[ct * 16 + cl];
        gam[ct] = g[ct * 16 + cl];
        bet[ct] = bln[ct * 16 + cl];
    }
#pragma unroll
    for (int rt = 0; rt < 2; rt++) {
        float sr[4], qr[4];
#pragma unroll
        for (int reg = 0; reg < 4; reg++) {
            float s = 0.0f, q = 0.0f;
#pragma unroll
            for (int ct = 0; ct < 8; ct++) {
                float v = acc[rt][ct][reg] + bias[ct];
                s += v;
                q += v * v;
            }
#pragma unroll
            for (int m = 1; m < 16; m <<= 1) {
                s += __shfl_xor(s, m);
                q += __shfl_xor(q, m);
            }
            sr[reg] = s;
            qr[reg] = q;
        }
#pragma unroll
        for (int reg = 0; reg < 4; reg++) {
            int row = m0 + rt * 16 + g4 * 4 + reg;
            if (row < N) {
                float mean = sr[reg] * (1.0f / 128.0f);
                float var = qr[reg] * (1.0f / 128.0f) - mean * mean;
                float rstd = rsqrtf(fmaxf(var, 0.0f) + 1e-5f);
#pragma unroll
                for (int ct = 0; ct < 8; ct++) {
                    float v = acc[rt][ct][reg] + bias[ct];
                    float r = fmaxf((v - mean) * rstd * gam[ct] + bet[ct], 0.0f);
                    int c = ct * 16 + cl;
                    size_t idx = (size_t)row * HH + c;
                    float nv = bf2f(hbin[idx]) + r;
                    hbout[idx] = f2bf(nv);
                    hf8out[(size_t)row * HH + permc(c)] = f2fp8(nv);
                }
            }
        }
    }
}

// ---------------- layer 3: fused gather + SAGE + pooling (no residual writes) ----------
// NOTE: shfl_xor(16|32) folds the 4 g4 quad-groups (8 DISTINCT rows each) ->
// result is already the wave count / column sum. No /16.

__global__ __launch_bounds__(256) void sage_pool_k(
    const ushort* __restrict__ hbin, const uchar* __restrict__ hf8in,
    const int* __restrict__ offs, const int* __restrict__ csr,
    const float* __restrict__ invd, const ushort* __restrict__ Bp,
    const float* __restrict__ bl, const float* __restrict__ g,
    const float* __restrict__ bln, const int* __restrict__ batch,
    float* __restrict__ psum, int* __restrict__ pmax, int* __restrict__ pcnt, int N) {
    __shared__ float wsum[4][128];
    __shared__ float wmax[4][128];
    __shared__ int wcnt[4];
    int tid = threadIdx.x;
    int wave = tid >> 6;
    int lane = tid & 63;
    int blk0 = blockIdx.x * 128;
    int m0 = blk0 + wave * 32;
    int am = lane & 15, aq = lane >> 4;

    short8 a_agg[2][4];
#pragma unroll
    for (int rt = 0; rt < 2; rt++) {
        int row = m0 + rt * 16 + am;
        row = row < N ? row : N - 1;
        gather_agg(hf8in, offs, csr, invd, row, aq, a_agg[rt]);
    }

    floatx4 acc[2][8];
#pragma unroll
    for (int rt = 0; rt < 2; rt++)
#pragma unroll
        for (int ct = 0; ct < 8; ct++) acc[rt][ct] = (floatx4)0.0f;

#pragma unroll
    for (int ks = 0; ks < 8; ks++) {
        short8 a[2];
        if (ks < 4) {
            a[0] = a_agg[0][ks];
            a[1] = a_agg[1][ks];
        } else {
            int kc = (ks & 3) * 32 + aq * 8;
#pragma unroll
            for (int rt = 0; rt < 2; rt++) {
                int row = m0 + rt * 16 + am;
                row = row < N ? row : N - 1;
                a[rt] = *(const short8*)(hbin + (size_t)row * HH + kc);
            }
        }
#pragma unroll
        for (int ct = 0; ct < 8; ct++) {
            short8 b = *(const short8*)(Bp + (((size_t)(ks * 8 + ct)) * 64 + lane) * 8);
            acc[0][ct] = __builtin_amdgcn_mfma_f32_16x16x32_bf16(a[0], b, acc[0][ct], 0, 0, 0);
            acc[1][ct] = __builtin_amdgcn_mfma_f32_16x16x32_bf16(a[1], b, acc[1][ct], 0, 0, 0);
        }
    }

    int g4 = lane >> 4, cl = lane & 15;
    float bias[8], gam[8], bet[8];
#pragma unroll
    for (int ct = 0; ct < 8; ct++) {
        bias[ct] = bl[ct * 16 + cl];
        gam[ct] = g[ct * 16 + cl];
        bet[ct] = bln[ct * 16 + cl];
    }
    // epilogue: nv = hbin + relu(LN(gemm+bias)), overwrite acc; rows >= N get 0
#pragma unroll
    for (int rt = 0; rt < 2; rt++) {
        float sr[4], qr[4];
#pragma unroll
        for (int reg = 0; reg < 4; reg++) {
            float s = 0.0f, q = 0.0f;
#pragma unroll
            for (int ct = 0; ct < 8; ct++) {
                float v = acc[rt][ct][reg] + bias[ct];
                s += v;
                q += v * v;
            }
#pragma unroll
            for (int m = 1; m < 16; m <<= 1) {
                s += __shfl_xor(s, m);
                q += __shfl_xor(q, m);
            }
            sr[reg] = s;
            qr[reg] = q;
        }
#pragma unroll
        for (int reg = 0; reg < 4; reg++) {
            int row = m0 + rt * 16 + g4 * 4 + reg;
            float mean = sr[reg] * (1.0f / 128.0f);
            float var = qr[reg] * (1.0f / 128.0f) - mean * mean;
            float rstd = rsqrtf(fmaxf(var, 0.0f) + 1e-5f);
            if (row < N) {
#pragma unroll
                for (int ct = 0; ct < 8; ct++) {
                    float v = acc[rt][ct][reg] + bias[ct];
                    float r = fmaxf((v - mean) * rstd * gam[ct] + bet[ct], 0.0f);
                    acc[rt][ct][reg] = bf2f(hbin[(size_t)row * HH + ct * 16 + cl]) + r;
                }
            } else {
#pragma unroll
                for (int ct = 0; ct < 8; ct++) acc[rt][ct][reg] = 0.0f;
            }
        }
    }

    bool fast = (blk0 + 127 < N) && (batch[blk0] == batch[blk0 + 127]);
    if (fast) {
        int b0 = batch[blk0];
#pragma unroll
        for (int ct = 0; ct < 8; ct++) {
            float s = 0.0f, m = 0.0f;
#pragma unroll
            for (int rt = 0; rt < 2; rt++)
#pragma unroll
                for (int reg = 0; reg < 4; reg++) {
                    float v = acc[rt][ct][reg];
                    s += v;
                    m = fmaxf(m, v);
                }
            s += __shfl_xor(s, 16); m = fmaxf(m, __shfl_xor(m, 16));
            s += __shfl_xor(s, 32); m = fmaxf(m, __shfl_xor(m, 32));
            if (g4 == 0) {
                wsum[wave][ct * 16 + cl] = s;
                wmax[wave][ct * 16 + cl] = m;
            }
        }
        __syncthreads();
        if (tid < 128) {
            float s = (wsum[0][tid] + wsum[1][tid]) + (wsum[2][tid] + wsum[3][tid]);
            float m = fmaxf(fmaxf(wmax[0][tid], wmax[1][tid]),
                            fmaxf(wmax[2][tid], wmax[3][tid]));
            atomicAdd(&psum[b0 * HH + tid], s);
            atomicMax(&pmax[b0 * HH + tid], __float_as_int(m));
        }
        if (tid == 0) atomicAdd(&pcnt[b0], 128);
    } else {
        int nlast = (blk0 + 127 < N - 1) ? blk0 + 127 : N - 1;
        int bfirst = batch[blk0];
        int blast = batch[nlast];
        int brow[2][4];
#pragma unroll
        for (int rt = 0; rt < 2; rt++)
#pragma unroll
            for (int reg = 0; reg < 4; reg++) {
                int row = m0 + rt * 16 + g4 * 4 + reg;
                brow[rt][reg] = (row < N) ? batch[row] : -1;
            }
        for (int b = bfirst; b <= blast; b++) {
            int c = 0;
#pragma unroll
            for (int rt = 0; rt < 2; rt++)
#pragma unroll
                for (int reg = 0; reg < 4; reg++) c += (brow[rt][reg] == b) ? 1 : 0;
            c += __shfl_xor(c, 16);
            c += __shfl_xor(c, 32);   // 4 g4 groups x 8 distinct rows = wave count
#pragma unroll
            for (int ct = 0; ct < 8; ct++) {
                float s = 0.0f, m = 0.0f;
#pragma unroll
                for (int rt = 0; rt < 2; rt++)
#pragma unroll
                    for (int reg = 0; reg < 4; reg++) {
                        if (brow[rt][reg] == b) {
                            float v = acc[rt][ct][reg];
                            s += v;
                            m = fmaxf(m, v);
                        }
                    }
                s += __shfl_xor(s, 16); m = fmaxf(m, __shfl_xor(m, 16));
                s += __shfl_xor(s, 32); m = fmaxf(m, __shfl_xor(m, 32));
                if (g4 == 0) {
                    wsum[wave][ct * 16 + cl] = s;
                    wmax[wave][ct * 16 + cl] = m;
                }
            }
            if (lane == 0) wcnt[wave] = c;
            __syncthreads();
            if (tid < 128) {
                float s = (wsum[0][tid] + wsum[1][tid]) + (wsum[2][tid] + wsum[3][tid]);
                float m = fmaxf(fmaxf(wmax[0][tid], wmax[1][tid]),
                                fmaxf(wmax[2][tid], wmax[3][tid]));
                atomicAdd(&psum[b * HH + tid], s);
                atomicMax(&pmax[b * HH + tid], __float_as_int(m));
            }
            if (tid == 0)
                atomicAdd(&pcnt[b], wcnt[0] + wcnt[1] + wcnt[2] + wcnt[3]);
            __syncthreads();
        }
    }
}

// ---------------- head: trackster MLP + concat + LN + classifier ----------------

__global__ __launch_bounds__(128) void head_k(
    const float* __restrict__ psum, const float* __restrict__ pmax,
    const int* __restrict__ pcnt, const float* __restrict__ ts,
    const float* __restrict__ tsW1, const float* __restrict__ tsb1,
    const float* __restrict__ tslng, const float* __restrict__ tslnb,
    const float* __restrict__ tsW2, const float* __restrict__ tsb2,
    const float* __restrict__ clng, const float* __restrict__ clnb,
    const float* __restrict__ cW1, const float* __restrict__ cb1,
    const float* __restrict__ cW2, const float* __restrict__ cb2,
    float* __restrict__ out) {
    int b = blockIdx.x;
    int t = threadIdx.x;
    __shared__ float feat[320];
    __shared__ float tn[64];
    __shared__ float zz[128];
    __shared__ float ps[2], pq[2];

    if (t < 64) {
        float v = tsb1[t];
#pragma unroll
        for (int k = 0; k < 3; k++) v = fmaf(ts[b * 3 + k], tsW1[k * 64 + t], v);
        float s = v, q = v * v;
#pragma unroll
        for (int m = 1; m < 64; m <<= 1) {
            s += __shfl_xor(s, m);
            q += __shfl_xor(q, m);
        }
        float mean = s * (1.0f / 64.0f);
        float var = q * (1.0f / 64.0f) - mean * mean;
        float rstd = rsqrtf(fmaxf(var, 0.0f) + 1e-5f);
        tn[t] = fmaxf((v - mean) * rstd * tslng[t] + tslnb[t], 0.0f);
    }
    __syncthreads();
    if (t < 64) {
        float v = tsb2[t];
        for (int k = 0; k < 64; k++) v = fmaf(tn[k], tsW2[k * 64 + t], v);
        feat[256 + t] = v;
    }
    float cntf = (float)(pcnt[b] > 1 ? pcnt[b] : 1);
    feat[t] = psum[b * HH + t] / cntf;
    feat[128 + t] = pmax[b * HH + t];
    __syncthreads();

    float s = 0.0f, q = 0.0f;
    for (int i = t; i < 320; i += 128) {
        float v = feat[i];
        s += v;
        q += v * v;
    }
#pragma unroll
    for (int m = 1; m < 64; m <<= 1) {
        s += __shfl_xor(s, m);
        q += __shfl_xor(q, m);
    }
    if ((t & 63) == 0) { ps[t >> 6] = s; pq[t >> 6] = q; }
    __syncthreads();
    float S = ps[0] + ps[1], Q = pq[0] + pq[1];
    float mean = S * (1.0f / 320.0f);
    float var = Q * (1.0f / 320.0f) - mean * mean;
    float rstd = rsqrtf(fmaxf(var, 0.0f) + 1e-5f);
    for (int i = t; i < 320; i += 128)
        feat[i] = (feat[i] - mean) * rstd * clng[i] + clnb[i];
    __syncthreads();

    {
        float v = cb1[t];
        for (int k = 0; k < 320; k++) v = fmaf(feat[k], cW1[k * HH + t], v);
        zz[t] = fmaxf(v, 0.0f);
    }
    __syncthreads();
    if (t < 8) {
        float v = cb2[t];
        for (int k = 0; k < 128; k++) v = fmaf(zz[k], cW2[k * 8 + t], v);
        out[b * 8 + t] = v;
    }
}

// ---------------- launcher ----------------

extern "C" void kernel_launch(void* const* d_in, const int* in_sizes, int n_in,
                              void* d_out, int out_size, void* d_ws, size_t ws_size,
                              hipStream_t stream) {
    const int N = in_sizes[0] / 4;
    const int E = in_sizes[1] / 2;
    const int B = in_sizes[3] / 3;
    const int nbuk = (N + BUK - 1) >> BUK_SH;   // <= 256 for N <= 131072

    const float* x    = (const float*)d_in[0];
    const int*   ei   = (const int*)d_in[1];
    const int*   srcv = ei;
    const int*   dstv = ei + E;
    const int*   batch = (const int*)d_in[2];
    const float* ts   = (const float*)d_in[3];
    const float* encW = (const float*)d_in[4];
    const float* encb = (const float*)d_in[5];
    const float* sageWl = (const float*)d_in[6];
    const float* sagebl = (const float*)d_in[7];
    const float* sageWr = (const float*)d_in[8];
    const float* lng  = (const float*)d_in[9];
    const float* lnb  = (const float*)d_in[10];
    const float* tsW1 = (const float*)d_in[11];
    const float* tsb1 = (const float*)d_in[12];
    const float* tslng = (const float*)d_in[13];
    const float* tslnb = (const float*)d_in[14];
    const float* tsW2 = (const float*)d_in[15];
    const float* tsb2 = (const float*)d_in[16];
    const float* clng = (const float*)d_in[17];
    const float* clnb = (const float*)d_in[18];
    const float* cW1  = (const float*)d_in[19];
    const float* cb1  = (const float*)d_in[20];
    const float* cW2  = (const float*)d_in[21];
    const float* cb2  = (const float*)d_in[22];
    float* out = (float*)d_out;

    char* w = (char*)d_ws;
    size_t off = 0;
    auto take = [&](size_t bytes) -> void* {
        void* p = w + off;
        off = (off + bytes + 255) & ~(size_t)255;
        return p;
    };
    uint*  hb0  = (uint*)take((size_t)N * HH * 2);    // bf16 residual (ping)
    uint*  hb1  = (uint*)take((size_t)N * HH * 2);    // bf16 residual (pong)
    uchar* hf80 = (uchar*)take((size_t)N * HH);       // fp8 frag-permuted mirror (ping)
    uchar* hf81 = (uchar*)take((size_t)N * HH);       // fp8 frag-permuted mirror (pong)
    ushort* Bp  = (ushort*)take((size_t)3 * HH * 2 * HH * 2); // packed weights
    int*   csr  = (int*)take((size_t)E * 4);
    int*   offs = (int*)take((size_t)(N + 1) * 4);
    float* invd = (float*)take((size_t)N * 4);
    uint*  ebuf = (uint*)take((size_t)nbuk * CAP * 4);
    // zero-initialized block (contiguous -> one memset)
    size_t z0 = off;
    int*   gcur = (int*)take(256 * 4);
    float* psum = (float*)take((size_t)B * HH * 4);
    int*   pmax = (int*)take((size_t)B * HH * 4);
    int*   pcnt = (int*)take((size_t)B * 4);
    size_t z1 = off;

    hipMemsetAsync(w + z0, 0, z1 - z0, stream);

    bin_k<<<(E + 2047) / 2048, 256, 0, stream>>>(srcv, dstv, gcur, ebuf, E);
    build_k<<<nbuk, 256, 0, stream>>>(ebuf, gcur, offs, invd, csr, N, nbuk);

    prep_w_k<<<384, 256, 0, stream>>>(sageWl, sageWr, Bp);
    encoder_k<<<(N + 3) / 4, 256, 0, stream>>>(x, encW, encb, hb0, hf80, N);

    int nblk = (N + 127) / 128;
    // layer 0: (hb0,hf80) -> (hb1,hf81) ; layer 1: (hb1,hf81) -> (hb0,hf80)
    sage_mfma_k<<<nblk, 256, 0, stream>>>(
        (const ushort*)hb0, hf80, (ushort*)hb1, hf81, offs, csr, invd, Bp,
        sagebl, lng, lnb, N);
    sage_mfma_k<<<nblk, 256, 0, stream>>>(
        (const ushort*)hb1, hf81, (ushort*)hb0, hf80, offs, csr, invd,
        Bp + (size_t)32768,
        sagebl + (size_t)HH, lng + (size_t)HH, lnb + (size_t)HH, N);
    // layer 2 fused with pooling: reads (hb0,hf80)
    sage_pool_k<<<nblk, 256, 0, stream>>>(
        (const ushort*)hb0, hf80, offs, csr, invd, Bp + (size_t)2 * 32768,
        sagebl + (size_t)2 * HH, lng + (size_t)2 * HH, lnb + (size_t)2 * HH,
        batch, psum, pmax, pcnt, N);

    head_k<<<B, 128, 0, stream>>>(psum, (const float*)pmax, pcnt, ts,
                                  tsW1, tsb1, tslng, tslnb, tsW2, tsb2,
                                  clng, clnb, cW1, cb1, cW2, cb2, out);
}